// Round 12
// baseline (48.819 us; speedup 1.0000x reference)
//
#include <hip/hip_runtime.h>

// GCNAggregator: B=4096 rows, K=32 neighbor indices into U=16384 node tables
// of D=256 f32. Set-semantics mask, symmetric GCN norm.
//   out_feats[b,:] = sum_{unique u in row b} feat[u,:] / (sqrt(rowcnt_b)*sqrt(colcnt_u))
// d_out = [to_feats (B*D) | to_noise (B*D)] f32.
//
// R12 = R8 + cold-path fixes. Budget (R9/R11 diagnostics): prep_cold ~12,
// gather1 ~26 (warm floor 19.3, R9), overhead ~1 => the slack is gather1's
// cold table reads. Theory: prep's dirty L2 lines write back to HBM (not L3)
// at kernel end; gather1 re-fetches 16 MiB scattered from HBM. Fixes:
//  - prep reads f32 source with NONTEMPORAL LOADS (never re-read; keep
//    L2/L3 capacity for packed lines)
//  - warmup node W: linear sweep of packed table (16 MiB, ~2.5 us) between
//    prep and gather to force writeback + L3 allocation; gather1 then hits L3.
// Chain: N1 prep_feat(+zero) -> N2 prep_noise(+colcount) -> W warm -> G gather.

#define B_ 4096
#define K_ 32
#define U_ 16384
#define D_ 256
#define HALF_SLOTS (U_ * D_ / 8)       // 524288 uint4 slots per table

typedef unsigned int uint4n __attribute__((ext_vector_type(4)));
typedef float float4n __attribute__((ext_vector_type(4)));

__device__ __forceinline__ unsigned bf16_rne(float x) {
    const unsigned u = __float_as_uint(x);
    return (u + 0x7FFFu + ((u >> 16) & 1u)) >> 16;
}
__device__ __forceinline__ unsigned pack2(float lo, float hi) {
    return bf16_rne(lo) | (bf16_rne(hi) << 16);
}
__device__ __forceinline__ float blo(unsigned v) { return __uint_as_float(v << 16); }
__device__ __forceinline__ float bhi(unsigned v) { return __uint_as_float(v & 0xFFFF0000u); }

__device__ __forceinline__ void conv_slot(const float4n* __restrict__ src,
                                          uint4n* __restrict__ packed,
                                          int t, int half_off) {
    const int u = t >> 5;
    const int s = t & 31;
    // nontemporal: source f32 is read exactly once, never again
    const float4n a = __builtin_nontemporal_load(&src[u * (D_ / 4) + s * 2]);
    const float4n b = __builtin_nontemporal_load(&src[u * (D_ / 4) + s * 2 + 1]);
    uint4n o;
    o.x = pack2(a.x, a.y);
    o.y = pack2(a.z, a.w);
    o.z = pack2(b.x, b.y);
    o.w = pack2(b.z, b.w);
    packed[u * 64 + half_off + s] = o;
}

// N1: zero colcnt + convert feat half.
__global__ __launch_bounds__(256) void gcn_prep_feat(const float4n* __restrict__ feat,
                                                     uint4n* __restrict__ packed,
                                                     int* __restrict__ colcnt) {
    const int gid = blockIdx.x * 256 + threadIdx.x;
    if (gid < U_) colcnt[gid] = 0;
    conv_slot(feat, packed, gid, 0);
}

// N2: convert noise half + colcount (first 4096 waves each count 1 row).
__global__ __launch_bounds__(256) void gcn_prep_noise(const int* __restrict__ idx,
                                                      const float4n* __restrict__ noise,
                                                      uint4n* __restrict__ packed,
                                                      int* __restrict__ colcnt) {
    const int gid = blockIdx.x * 256 + threadIdx.x;
    conv_slot(noise, packed, gid, 32);

    const int wg = gid >> 6;
    if (wg < B_) {
        const int lane = threadIdx.x & 63;
        const int kk = lane & 31;
        const int u = idx[wg * K_ + kk];
        bool dup = false;
        #pragma unroll
        for (int j = 0; j < K_; ++j) {
            const int uj = __shfl(u, j);
            if (j < kk && uj == u) dup = true;
        }
        if (lane < 32 && !dup) atomicAdd(&colcnt[u], 1);
    }
}

// W: linear warm sweep of the packed table -> forces dirty-L2 writeback and
// L3 allocation so the gather's first random pass hits L3 instead of HBM.
// 512 blocks x 256 thr x 8 uint4 each = 16 MiB.
__global__ __launch_bounds__(256) void gcn_warm(const uint4n* __restrict__ packed) {
    const int gid = blockIdx.x * 256 + threadIdx.x;
    unsigned acc = 0;
    #pragma unroll
    for (int i = 0; i < 8; ++i) {
        const uint4n v = packed[(size_t)i * (512 * 256) + gid];
        acc ^= v.x ^ v.y ^ v.z ^ v.w;
    }
    asm volatile("" :: "v"(acc));   // keep loads live (no DCE), no store needed
}

// G: gather. One wave per row; lanes 0..31 feat dims, 32..63 noise dims.
__global__ __launch_bounds__(256) void gcn_gather(const int* __restrict__ idx,
                                                  const uint4n* __restrict__ packed,
                                                  const int* __restrict__ colcnt,
                                                  float4* __restrict__ out) {
    const int row = blockIdx.x * 4 + (threadIdx.x >> 6);
    const int lane = threadIdx.x & 63;

    const int kk = lane & 31;
    const int u = idx[row * K_ + kk];

    bool dup = false;
    #pragma unroll
    for (int j = 0; j < K_; ++j) {
        const int uj = __shfl(u, j);
        if (j < kk && uj == u) dup = true;
    }
    const int rowcnt = __popcll(__ballot(!dup) & 0xFFFFFFFFull);

    float w = 0.0f;
    if (!dup) w = rsqrtf((float)(rowcnt * colcnt[u]));

    int us[K_]; float wk[K_];
    #pragma unroll
    for (int k = 0; k < K_; ++k) {
        us[k] = __builtin_amdgcn_readlane(u, k);
        wk[k] = __uint_as_float(
            (unsigned)__builtin_amdgcn_readlane((int)__float_as_uint(w), k));
    }

    float a0 = 0.f, a1 = 0.f, a2 = 0.f, a3 = 0.f;
    float a4 = 0.f, a5 = 0.f, a6 = 0.f, a7 = 0.f;

    #pragma unroll
    for (int k = 0; k < K_; ++k) {
        const uint4n v = packed[us[k] * 64 + lane];
        const float wkk = wk[k];
        a0 = fmaf(wkk, blo(v.x), a0);
        a1 = fmaf(wkk, bhi(v.x), a1);
        a2 = fmaf(wkk, blo(v.y), a2);
        a3 = fmaf(wkk, bhi(v.y), a3);
        a4 = fmaf(wkk, blo(v.z), a4);
        a5 = fmaf(wkk, bhi(v.z), a5);
        a6 = fmaf(wkk, blo(v.w), a6);
        a7 = fmaf(wkk, bhi(v.w), a7);
    }

    const int base = (lane < 32)
        ? (row * (D_ / 4) + lane * 2)
        : (B_ * (D_ / 4) + row * (D_ / 4) + (lane - 32) * 2);
    out[base]     = make_float4(a0, a1, a2, a3);
    out[base + 1] = make_float4(a4, a5, a6, a7);
}

extern "C" void kernel_launch(void* const* d_in, const int* in_sizes, int n_in,
                              void* d_out, int out_size, void* d_ws, size_t ws_size,
                              hipStream_t stream) {
    const int*     idx   = (const int*)d_in[0];        // [B,K] int32
    const float4n* feat  = (const float4n*)d_in[1];    // [U,D] f32
    const float4n* noise = (const float4n*)d_in[2];    // [U,D] f32
    float4*        out   = (float4*)d_out;             // [2*B, D] f32

    uint4n* packed = (uint4n*)d_ws;                    // 16 MiB packed bf16 table
    int*    colcnt = (int*)((char*)d_ws + 32u * 1024 * 1024);  // 64 KiB

    gcn_prep_feat <<<HALF_SLOTS / 256, 256, 0, stream>>>(feat, packed, colcnt);
    gcn_prep_noise<<<HALF_SLOTS / 256, 256, 0, stream>>>(idx, noise, packed, colcnt);
    gcn_warm      <<<512,              256, 0, stream>>>(packed);
    gcn_gather    <<<B_ / 4,           256, 0, stream>>>(idx, packed, colcnt, out);
}

// Round 13
// 45.035 us; speedup vs baseline: 1.0840x; 1.0840x over previous
//
#include <hip/hip_runtime.h>

// GCNAggregator: B=4096 rows, K=32 neighbor indices into U=16384 node tables
// of D=256 f32. Set-semantics mask, symmetric GCN norm.
//   out_feats[b,:] = sum_{unique u in row b} feat[u,:] / (sqrt(rowcnt_b)*sqrt(colcnt_u))
// d_out = [to_feats (B*D) | to_noise (B*D)] f32.
//
// R13 = R8 (exact) + warm node ONLY — deconfounds R12 (which changed nt loads
// AND warm together). R8 chain: N1 prep_feat(+zero), N2 prep_noise(+colcount),
// G gather. Here: N1 -> N2 -> W(linear 16 MiB read of packed) -> G.
// If W forces dirty-L2 writeback to L3, gather1 runs ~20-21 us -> total ~37.
// If cross-XCD dirty lines are serviced cache-to-cache (stay dirty), W is
// useless -> total ~44 -> revert to R8 and declare roofline.

#define B_ 4096
#define K_ 32
#define U_ 16384
#define D_ 256
#define HALF_SLOTS (U_ * D_ / 8)       // 524288 uint4 slots per table

typedef unsigned int uint4n __attribute__((ext_vector_type(4)));

__device__ __forceinline__ unsigned bf16_rne(float x) {
    const unsigned u = __float_as_uint(x);
    return (u + 0x7FFFu + ((u >> 16) & 1u)) >> 16;
}
__device__ __forceinline__ unsigned pack2(float lo, float hi) {
    return bf16_rne(lo) | (bf16_rne(hi) << 16);
}
__device__ __forceinline__ float blo(unsigned v) { return __uint_as_float(v << 16); }
__device__ __forceinline__ float bhi(unsigned v) { return __uint_as_float(v & 0xFFFF0000u); }

// regular loads (source stays L3-resident across replays), nt stores (as R8)
__device__ __forceinline__ void conv_slot(const float4* __restrict__ src,
                                          uint4n* __restrict__ packed,
                                          int t, int half_off) {
    const int u = t >> 5;
    const int s = t & 31;
    const float4 a = src[u * (D_ / 4) + s * 2];
    const float4 b = src[u * (D_ / 4) + s * 2 + 1];
    uint4n o;
    o.x = pack2(a.x, a.y);
    o.y = pack2(a.z, a.w);
    o.z = pack2(b.x, b.y);
    o.w = pack2(b.z, b.w);
    __builtin_nontemporal_store(o, &packed[u * 64 + half_off + s]);
}

// N1: zero colcnt + convert feat half.
__global__ __launch_bounds__(256) void gcn_prep_feat(const float4* __restrict__ feat,
                                                     uint4n* __restrict__ packed,
                                                     int* __restrict__ colcnt) {
    const int gid = blockIdx.x * 256 + threadIdx.x;
    if (gid < U_) colcnt[gid] = 0;
    conv_slot(feat, packed, gid, 0);
}

// N2: convert noise half + colcount (first 4096 waves each count 1 row).
__global__ __launch_bounds__(256) void gcn_prep_noise(const int* __restrict__ idx,
                                                      const float4* __restrict__ noise,
                                                      uint4n* __restrict__ packed,
                                                      int* __restrict__ colcnt) {
    const int gid = blockIdx.x * 256 + threadIdx.x;
    conv_slot(noise, packed, gid, 32);

    const int wg = gid >> 6;
    if (wg < B_) {
        const int lane = threadIdx.x & 63;
        const int kk = lane & 31;
        const int u = idx[wg * K_ + kk];
        bool dup = false;
        #pragma unroll
        for (int j = 0; j < K_; ++j) {
            const int uj = __shfl(u, j);
            if (j < kk && uj == u) dup = true;
        }
        if (lane < 32 && !dup) atomicAdd(&colcnt[u], 1);
    }
}

// W: linear sweep of the packed table (16 MiB) — remote reads of the dirty
// lines should clean them into L3 so gather1 avoids cross-XCD dirty misses.
// 2048 blocks x 256 thr x 2 uint4.
__global__ __launch_bounds__(256) void gcn_warm(const uint4n* __restrict__ packed) {
    const int gid = blockIdx.x * 256 + threadIdx.x;
    unsigned acc = 0;
    #pragma unroll
    for (int i = 0; i < 2; ++i) {
        const uint4n v = packed[(size_t)i * (2048 * 256) + gid];
        acc ^= v.x ^ v.y ^ v.z ^ v.w;
    }
    asm volatile("" :: "v"(acc));   // keep loads live, no store
}

// G: gather. One wave per row; lanes 0..31 feat dims, 32..63 noise dims.
__global__ __launch_bounds__(256) void gcn_gather(const int* __restrict__ idx,
                                                  const uint4n* __restrict__ packed,
                                                  const int* __restrict__ colcnt,
                                                  float4* __restrict__ out) {
    const int row = blockIdx.x * 4 + (threadIdx.x >> 6);
    const int lane = threadIdx.x & 63;

    const int kk = lane & 31;
    const int u = idx[row * K_ + kk];

    bool dup = false;
    #pragma unroll
    for (int j = 0; j < K_; ++j) {
        const int uj = __shfl(u, j);
        if (j < kk && uj == u) dup = true;
    }
    const int rowcnt = __popcll(__ballot(!dup) & 0xFFFFFFFFull);

    float w = 0.0f;
    if (!dup) w = rsqrtf((float)(rowcnt * colcnt[u]));

    int us[K_]; float wk[K_];
    #pragma unroll
    for (int k = 0; k < K_; ++k) {
        us[k] = __builtin_amdgcn_readlane(u, k);
        wk[k] = __uint_as_float(
            (unsigned)__builtin_amdgcn_readlane((int)__float_as_uint(w), k));
    }

    float a0 = 0.f, a1 = 0.f, a2 = 0.f, a3 = 0.f;
    float a4 = 0.f, a5 = 0.f, a6 = 0.f, a7 = 0.f;

    #pragma unroll
    for (int k = 0; k < K_; ++k) {
        const uint4n v = packed[us[k] * 64 + lane];
        const float wkk = wk[k];
        a0 = fmaf(wkk, blo(v.x), a0);
        a1 = fmaf(wkk, bhi(v.x), a1);
        a2 = fmaf(wkk, blo(v.y), a2);
        a3 = fmaf(wkk, bhi(v.y), a3);
        a4 = fmaf(wkk, blo(v.z), a4);
        a5 = fmaf(wkk, bhi(v.z), a5);
        a6 = fmaf(wkk, blo(v.w), a6);
        a7 = fmaf(wkk, bhi(v.w), a7);
    }

    const int base = (lane < 32)
        ? (row * (D_ / 4) + lane * 2)
        : (B_ * (D_ / 4) + row * (D_ / 4) + (lane - 32) * 2);
    out[base]     = make_float4(a0, a1, a2, a3);
    out[base + 1] = make_float4(a4, a5, a6, a7);
}

extern "C" void kernel_launch(void* const* d_in, const int* in_sizes, int n_in,
                              void* d_out, int out_size, void* d_ws, size_t ws_size,
                              hipStream_t stream) {
    const int*    idx   = (const int*)d_in[0];        // [B,K] int32
    const float4* feat  = (const float4*)d_in[1];     // [U,D] f32
    const float4* noise = (const float4*)d_in[2];     // [U,D] f32
    float4*       out   = (float4*)d_out;             // [2*B, D] f32

    uint4n* packed = (uint4n*)d_ws;                   // 16 MiB packed bf16 table
    int*    colcnt = (int*)((char*)d_ws + 32u * 1024 * 1024);  // 64 KiB

    gcn_prep_feat <<<HALF_SLOTS / 256, 256, 0, stream>>>(feat, packed, colcnt);
    gcn_prep_noise<<<HALF_SLOTS / 256, 256, 0, stream>>>(idx, noise, packed, colcnt);
    gcn_warm      <<<2048,             256, 0, stream>>>(packed);
    gcn_gather    <<<B_ / 4,           256, 0, stream>>>(idx, packed, colcnt, out);
}

// Round 14
// 40.377 us; speedup vs baseline: 1.2091x; 1.1154x over previous
//
#include <hip/hip_runtime.h>

// GCNAggregator: B=4096 rows, K=32 neighbor indices into U=16384 node tables
// of D=256 f32. Set-semantics mask, symmetric GCN norm.
//   out_feats[b,:] = sum_{unique u in row b} feat[u,:] / (sqrt(rowcnt_b)*sqrt(colcnt_u))
// d_out = [to_feats (B*D) | to_noise (B*D)] f32.
//
// FINAL (== R8, the measured optimum at 40.0 us). Structure:
//   N1 prep_feat : zero colcnt + convert feat->bf16 half
//   N2 prep_noise: convert noise->bf16 half + colcount (hidden in N2)
//   N3 gather    : one dwordx4/lane/k from packed table [U][1 KiB]
// Packed table = {feat 512B | noise 512B} bf16 rows; gather traffic 128 MiB.
//
// Measured decomposition (R9/R11/R13 diagnostics):
//   prep chain (warm)       8.8 us   (48 MiB @ ~5.5 TB/s)
//   gather (warm floor)    19.3 us   (136 MiB @ ~6.8 TB/s = scatter ceiling)
//   first-pass cold premium ~7-10 us (structural: cross-XCD dirty lines;
//        phasing, nt/regular stores, and two L3-warm schemes all neutral)
// => ~37-39 us composed floor vs 40.0 measured. bf16 is the last precision
// step inside the 0.0355 absmax threshold (fp8 tail ~0.06), so bytes are
// minimal. Roofline.

#define B_ 4096
#define K_ 32
#define U_ 16384
#define D_ 256
#define HALF_SLOTS (U_ * D_ / 8)       // 524288 uint4 slots per table

typedef unsigned int uint4n __attribute__((ext_vector_type(4)));

__device__ __forceinline__ unsigned bf16_rne(float x) {
    const unsigned u = __float_as_uint(x);
    return (u + 0x7FFFu + ((u >> 16) & 1u)) >> 16;
}
__device__ __forceinline__ unsigned pack2(float lo, float hi) {
    return bf16_rne(lo) | (bf16_rne(hi) << 16);
}
__device__ __forceinline__ float blo(unsigned v) { return __uint_as_float(v << 16); }
__device__ __forceinline__ float bhi(unsigned v) { return __uint_as_float(v & 0xFFFF0000u); }

__device__ __forceinline__ void conv_slot(const float4* __restrict__ src,
                                          uint4n* __restrict__ packed,
                                          int t, int half_off) {
    const int u = t >> 5;
    const int s = t & 31;
    const float4 a = src[u * (D_ / 4) + s * 2];
    const float4 b = src[u * (D_ / 4) + s * 2 + 1];
    uint4n o;
    o.x = pack2(a.x, a.y);
    o.y = pack2(a.z, a.w);
    o.z = pack2(b.x, b.y);
    o.w = pack2(b.z, b.w);
    __builtin_nontemporal_store(o, &packed[u * 64 + half_off + s]);
}

// N1: zero colcnt + convert feat half.
__global__ __launch_bounds__(256) void gcn_prep_feat(const float4* __restrict__ feat,
                                                     uint4n* __restrict__ packed,
                                                     int* __restrict__ colcnt) {
    const int gid = blockIdx.x * 256 + threadIdx.x;
    if (gid < U_) colcnt[gid] = 0;
    conv_slot(feat, packed, gid, 0);
}

// N2: convert noise half + colcount (first 4096 waves each count 1 row).
__global__ __launch_bounds__(256) void gcn_prep_noise(const int* __restrict__ idx,
                                                      const float4* __restrict__ noise,
                                                      uint4n* __restrict__ packed,
                                                      int* __restrict__ colcnt) {
    const int gid = blockIdx.x * 256 + threadIdx.x;
    conv_slot(noise, packed, gid, 32);

    const int wg = gid >> 6;
    if (wg < B_) {
        const int lane = threadIdx.x & 63;
        const int kk = lane & 31;            // lanes 32..63 mirror 0..31
        const int u = idx[wg * K_ + kk];
        bool dup = false;
        #pragma unroll
        for (int j = 0; j < K_; ++j) {
            const int uj = __shfl(u, j);
            if (j < kk && uj == u) dup = true;   // first occurrence wins
        }
        if (lane < 32 && !dup) atomicAdd(&colcnt[u], 1);
    }
}

// N3: gather. One wave per row; lanes 0..31 feat dims, 32..63 noise dims.
__global__ __launch_bounds__(256) void gcn_gather(const int* __restrict__ idx,
                                                  const uint4n* __restrict__ packed,
                                                  const int* __restrict__ colcnt,
                                                  float4* __restrict__ out) {
    const int row = blockIdx.x * 4 + (threadIdx.x >> 6);
    const int lane = threadIdx.x & 63;

    const int kk = lane & 31;
    const int u = idx[row * K_ + kk];

    bool dup = false;
    #pragma unroll
    for (int j = 0; j < K_; ++j) {
        const int uj = __shfl(u, j);
        if (j < kk && uj == u) dup = true;
    }
    const int rowcnt = __popcll(__ballot(!dup) & 0xFFFFFFFFull);

    float w = 0.0f;
    if (!dup) w = rsqrtf((float)(rowcnt * colcnt[u]));

    // broadcast all 32 (u,w) to SGPRs (compile-time readlane)
    int us[K_]; float wk[K_];
    #pragma unroll
    for (int k = 0; k < K_; ++k) {
        us[k] = __builtin_amdgcn_readlane(u, k);
        wk[k] = __uint_as_float(
            (unsigned)__builtin_amdgcn_readlane((int)__float_as_uint(w), k));
    }

    float a0 = 0.f, a1 = 0.f, a2 = 0.f, a3 = 0.f;
    float a4 = 0.f, a5 = 0.f, a6 = 0.f, a7 = 0.f;

    #pragma unroll
    for (int k = 0; k < K_; ++k) {
        const uint4n v = packed[us[k] * 64 + lane];
        const float wkk = wk[k];
        a0 = fmaf(wkk, blo(v.x), a0);
        a1 = fmaf(wkk, bhi(v.x), a1);
        a2 = fmaf(wkk, blo(v.y), a2);
        a3 = fmaf(wkk, bhi(v.y), a3);
        a4 = fmaf(wkk, blo(v.z), a4);
        a5 = fmaf(wkk, bhi(v.z), a5);
        a6 = fmaf(wkk, blo(v.w), a6);
        a7 = fmaf(wkk, bhi(v.w), a7);
    }

    // lanes 0..31: to_feats[row][lane*8..+8); lanes 32..63: to_noise same dims
    const int base = (lane < 32)
        ? (row * (D_ / 4) + lane * 2)
        : (B_ * (D_ / 4) + row * (D_ / 4) + (lane - 32) * 2);
    out[base]     = make_float4(a0, a1, a2, a3);
    out[base + 1] = make_float4(a4, a5, a6, a7);
}

extern "C" void kernel_launch(void* const* d_in, const int* in_sizes, int n_in,
                              void* d_out, int out_size, void* d_ws, size_t ws_size,
                              hipStream_t stream) {
    const int*    idx   = (const int*)d_in[0];        // [B,K] int32
    const float4* feat  = (const float4*)d_in[1];     // [U,D] f32
    const float4* noise = (const float4*)d_in[2];     // [U,D] f32
    float4*       out   = (float4*)d_out;             // [2*B, D] f32

    uint4n* packed = (uint4n*)d_ws;                   // 16 MiB packed bf16 table
    int*    colcnt = (int*)((char*)d_ws + 32u * 1024 * 1024);  // 64 KiB

    gcn_prep_feat <<<HALF_SLOTS / 256, 256, 0, stream>>>(feat, packed, colcnt);
    gcn_prep_noise<<<HALF_SLOTS / 256, 256, 0, stream>>>(idx, noise, packed, colcnt);
    gcn_gather    <<<B_ / 4,          256, 0, stream>>>(idx, packed, colcnt, out);
}